// Round 6
// baseline (940.691 us; speedup 1.0000x reference)
//
#include <hip/hip_runtime.h>
#include <math.h>

// Problem constants
#define BATCH 4
#define SEQ   1024
#define DIM   1024
#define HEADS 16
#define HD    64
#define NEXP  2
#define NSLOT 512
#define ES    1024       // NEXP*NSLOT
#define HID   4096
#define LNEPS 1e-5f
#define NTOK  (BATCH*SEQ)

typedef long long ll;
typedef unsigned short ushort;
typedef unsigned int uint;
typedef __attribute__((ext_vector_type(8))) short short8;   // 8 bf16 (4 VGPRs)
typedef __attribute__((ext_vector_type(4))) float f32x4;    // MFMA accum
typedef __attribute__((ext_vector_type(4))) unsigned short us4;

__device__ __forceinline__ ushort f2b(float f) {            // fp32 -> bf16 RNE
    uint u = __builtin_bit_cast(uint, f);
    u += 0x7FFFu + ((u >> 16) & 1u);
    return (ushort)(u >> 16);
}
__device__ __forceinline__ float b2f(ushort h) {
    uint u = ((uint)h) << 16;
    return __builtin_bit_cast(float, u);
}
__device__ __forceinline__ uint pk(float a, float b) {
    return (uint)f2b(a) | ((uint)f2b(b) << 16);
}
__device__ __forceinline__ float gelu_f(float v) {
    float x3 = v * v * v;
    return 0.5f * v * (1.f + tanhf(0.7978845608028654f * (v + 0.044715f * x3)));
}

// async global->LDS, 16B per lane.  LDS dest must be wave-uniform base + lane*16.
__device__ __forceinline__ void gload16(const ushort* g, ushort* l) {
    __builtin_amdgcn_global_load_lds(
        (const __attribute__((address_space(1))) unsigned int*)(const void*)g,
        (__attribute__((address_space(3))) unsigned int*)(void*)l,
        16, 0, 0);
}

// ---------------------------------------------------------------------------
// fp32 -> bf16 elementwise convert, 8 elems/thread (x: 4M elems, grid 2048)
// ---------------------------------------------------------------------------
__global__ __launch_bounds__(256) void cvt_bf16(
    const float* __restrict__ src, ushort* __restrict__ dst)
{
    int i = blockIdx.x * 256 + threadIdx.x;
    const float4* s = reinterpret_cast<const float4*>(src) + (ll)i * 2;
    float4 a = s[0], b = s[1];
    uint4 w;
    w.x = pk(a.x, a.y); w.y = pk(a.z, a.w);
    w.z = pk(b.x, b.y); w.w = pk(b.z, b.w);
    reinterpret_cast<uint4*>(dst)[i] = w;
}

// bias concat: o[0..1023] = a, o[1024..3071] = b   (grid 12)
__global__ __launch_bounds__(256) void concat_bias(
    const float* __restrict__ a, const float* __restrict__ b,
    float* __restrict__ o)
{
    int i = blockIdx.x * 256 + threadIdx.x;
    o[i] = (i < DIM) ? a[i] : b[i - DIM];
}

// ---------------------------------------------------------------------------
// Tiled transpose(+convert): dst[c][r] = TD(src[r][c]).  64x64 tiles.
// ---------------------------------------------------------------------------
template<typename TS, typename TD>
__global__ __launch_bounds__(256) void transpose_cvt(
    const TS* __restrict__ src, int ldsrc, ll sS1, ll sS2,
    TD* __restrict__ dst, int lddst, ll sD1, ll sD2, int Z2)
{
    __shared__ TD tile[64][68];
    const int z1 = blockIdx.z / Z2, z2 = blockIdx.z % Z2;
    src += z1 * sS1 + z2 * sS2;
    dst += z1 * sD1 + z2 * sD2;
    const int r0 = blockIdx.y * 64, c0 = blockIdx.x * 64;
    const int t = threadIdx.x;
    #pragma unroll
    for (int j = 0; j < 4; j++) {
        int idx = t + 256 * j;
        int r = idx >> 4, c = (idx & 15) * 4;
        if constexpr (sizeof(TS) == 4 && sizeof(TD) == 2) {
            float4 v = *reinterpret_cast<const float4*>(src + (ll)(r0 + r) * ldsrc + c0 + c);
            tile[r][c]     = f2b(v.x);
            tile[r][c + 1] = f2b(v.y);
            tile[r][c + 2] = f2b(v.z);
            tile[r][c + 3] = f2b(v.w);
        } else if constexpr (sizeof(TS) == 4 && sizeof(TD) == 4) {
            float4 v = *reinterpret_cast<const float4*>(src + (ll)(r0 + r) * ldsrc + c0 + c);
            *reinterpret_cast<float4*>(&tile[r][c]) = v;
        } else {
            *reinterpret_cast<us4*>(&tile[r][c]) =
                *reinterpret_cast<const us4*>(src + (ll)(r0 + r) * ldsrc + c0 + c);
        }
    }
    __syncthreads();
    #pragma unroll
    for (int j = 0; j < 4; j++) {
        int idx = t + 256 * j;
        int rr = idx >> 4, cc = (idx & 15) * 4;
        if constexpr (sizeof(TD) == 2) {
            us4 w;
            w.x = tile[cc][rr]; w.y = tile[cc + 1][rr];
            w.z = tile[cc + 2][rr]; w.w = tile[cc + 3][rr];
            *reinterpret_cast<us4*>(&dst[(ll)(c0 + rr) * lddst + r0 + cc]) = w;
        } else {
            float4 w;
            w.x = tile[cc][rr]; w.y = tile[cc + 1][rr];
            w.z = tile[cc + 2][rr]; w.w = tile[cc + 3][rr];
            *reinterpret_cast<float4*>(&dst[(ll)(c0 + rr) * lddst + r0 + cc]) = w;
        }
    }
}

// ---------------------------------------------------------------------------
// gemm2d: double-buffered pipelined MFMA bf16 GEMM.
//   C[M,N] = act(alpha * A@B^T + bias);  A [M][K], B [N][K] bf16 K-contig.
//   256 threads = 4 waves (2x2), wave tile 64 x (BN/2).  BK=64.
//   NBUF=2: 64/48 KiB LDS -> 2-3 blocks/CU;  NBUF=1 only for K==64 (NK=1).
// Loop (catalog minimal 2-phase, T3/T4/T5):
//   stage(kt+1) -> ds_read(kt) -> lgkmcnt(0) -> setprio(1)+MFMA
//   -> vmcnt(0) -> s_barrier         (ONE barrier per K-tile)
// Hazards: reads of buf[(kt+1)%2] retired before end-of-(kt-1) barrier;
// stage(kt+1) issued only after that barrier; end-of-kt vmcnt(0)+barrier
// makes the staged buffer collectively visible before iter kt+1 reads it.
// ---------------------------------------------------------------------------
template<int BM, int BN, int NBUF, int ACT, typename TC>
__global__ __launch_bounds__(256) void gemm2d(
    const ushort* __restrict__ A, int lda, ll sA1, ll sA2,
    const ushort* __restrict__ B, int ldb, ll sB1, ll sB2,
    const float* __restrict__ bias, ll sb1, ll sb2,
    TC* __restrict__ C, int ldc, ll sC1, ll sC2,
    int K, int Z2, float alpha)
{
    constexpr int MI = BM / 32;      // 4: row frags per wave (2 row-waves)
    constexpr int NI = BN / 32;      // 4 or 2: col frags per wave (2 col-waves)
    constexpr int LA = BM / 32;      // stage passes for A (32 rows / pass)
    constexpr int LB = BN / 32;

    __shared__ alignas(16) ushort As[NBUF][BM * 64];
    __shared__ alignas(16) ushort Bs[NBUF][BN * 64];

    const int z1 = blockIdx.z / Z2, z2 = blockIdx.z % Z2;
    A += z1 * sA1 + z2 * sA2;
    B += z1 * sB1 + z2 * sB2;
    C += z1 * sC1 + z2 * sC2;

    const int t = threadIdx.x;
    const int lane = t & 63, wave = t >> 6;
    const int quad = lane >> 4, l16 = lane & 15;
    const int wm = wave >> 1, wn = wave & 1;
    const int m0 = blockIdx.y * BM, n0 = blockIdx.x * BN;

    auto stageA = [&](int kt) {
        const ushort* src = A + (ll)m0 * lda + kt * 64;
        ushort* dst = As[kt & (NBUF - 1)];
        #pragma unroll
        for (int j = 0; j < LA; j++) {
            int seg = j * 256 + t;
            int row = seg >> 3, kk = (seg & 7) * 8;
            gload16(src + (ll)row * lda + kk, dst + seg * 8);
        }
    };
    auto stageB = [&](int kt) {
        const ushort* src = B + (ll)n0 * ldb + kt * 64;
        ushort* dst = Bs[kt & (NBUF - 1)];
        #pragma unroll
        for (int j = 0; j < LB; j++) {
            int seg = j * 256 + t;
            int row = seg >> 3, kk = (seg & 7) * 8;
            gload16(src + (ll)row * ldb + kk, dst + seg * 8);
        }
    };

    f32x4 acc[MI][NI] = {};
    const int NK = K / 64;

    stageA(0); stageB(0);
    asm volatile("s_waitcnt vmcnt(0)" ::: "memory");
    __builtin_amdgcn_sched_barrier(0);
    __builtin_amdgcn_s_barrier();
    __builtin_amdgcn_sched_barrier(0);

    for (int kt = 0; kt < NK; kt++) {
        // issue next tile's DMA first (overlaps the whole compute body)
        if (kt + 1 < NK) { stageA(kt + 1); stageB(kt + 1); }

        const ushort* Abuf = As[kt & (NBUF - 1)];
        const ushort* Bbuf = Bs[kt & (NBUF - 1)];
        short8 a[MI][2], b[NI][2];
        #pragma unroll
        for (int mi = 0; mi < MI; mi++)
            #pragma unroll
            for (int kh = 0; kh < 2; kh++)
                a[mi][kh] = *reinterpret_cast<const short8*>(
                    &Abuf[(wm * 64 + mi * 16 + l16) * 64 + kh * 32 + quad * 8]);
        #pragma unroll
        for (int ni = 0; ni < NI; ni++)
            #pragma unroll
            for (int kh = 0; kh < 2; kh++)
                b[ni][kh] = *reinterpret_cast<const short8*>(
                    &Bbuf[(wn * NI * 16 + ni * 16 + l16) * 64 + kh * 32 + quad * 8]);
        asm volatile("s_waitcnt lgkmcnt(0)" ::: "memory");
        __builtin_amdgcn_sched_barrier(0);
        __builtin_amdgcn_s_setprio(1);
        #pragma unroll
        for (int mi = 0; mi < MI; mi++)
            #pragma unroll
            for (int ni = 0; ni < NI; ni++)
                #pragma unroll
                for (int kh = 0; kh < 2; kh++)
                    acc[mi][ni] = __builtin_amdgcn_mfma_f32_16x16x32_bf16(
                        a[mi][kh], b[ni][kh], acc[mi][ni], 0, 0, 0);
        __builtin_amdgcn_s_setprio(0);
        __builtin_amdgcn_sched_barrier(0);

        if (kt + 1 < NK) {
            asm volatile("s_waitcnt vmcnt(0)" ::: "memory");
            __builtin_amdgcn_sched_barrier(0);
            __builtin_amdgcn_s_barrier();
            __builtin_amdgcn_sched_barrier(0);
        }
    }

    const float* bz = bias ? (bias + z1 * sb1 + z2 * sb2) : nullptr;
    #pragma unroll
    for (int mi = 0; mi < MI; mi++) {
        #pragma unroll
        for (int ni = 0; ni < NI; ni++) {
            const int row = m0 + wm * 64 + mi * 16 + quad * 4;
            const int col = n0 + wn * NI * 16 + ni * 16 + l16;
            const float bv = bz ? bz[col] : 0.f;
            #pragma unroll
            for (int r = 0; r < 4; r++) {
                float v = alpha * acc[mi][ni][r] + bv;
                if (ACT) v = gelu_f(v);
                if constexpr (sizeof(TC) == 2)
                    C[(ll)(row + r) * ldc + col] = f2b(v);
                else
                    C[(ll)(row + r) * ldc + col] = v;
            }
        }
    }
}

// ---------------------------------------------------------------------------
// Attention softmax over m, v3 (unchanged).
// ---------------------------------------------------------------------------
__global__ __launch_bounds__(256) void attn_softmax(
    ushort* __restrict__ p, float* __restrict__ attn_out)
{
    __shared__ float tile[16][1024];
    const int n = blockIdx.x, b = blockIdx.y;
    const int t = threadIdx.x;
    const int lane = t & 63, w = t >> 6;
    ushort* base = p + ((ll)(b * SEQ + n) * HEADS) * SEQ;
    #pragma unroll 1
    for (int g = 0; g < 4; g++) {
        const int h = g * 4 + w;
        ushort* row = base + (ll)h * SEQ + lane * 16;
        uint4 r0 = reinterpret_cast<const uint4*>(row)[0];
        uint4 r1 = reinterpret_cast<const uint4*>(row)[1];
        uint rr[8] = {r0.x, r0.y, r0.z, r0.w, r1.x, r1.y, r1.z, r1.w};
        float v[16];
        float m = -3.0e38f;
        #pragma unroll
        for (int j = 0; j < 8; j++) {
            v[2 * j]     = b2f((ushort)(rr[j] & 0xFFFFu));
            v[2 * j + 1] = b2f((ushort)(rr[j] >> 16));
            m = fmaxf(m, fmaxf(v[2 * j], v[2 * j + 1]));
        }
        #pragma unroll
        for (int o = 32; o; o >>= 1) m = fmaxf(m, __shfl_xor(m, o));
        float s = 0.f;
        #pragma unroll
        for (int j = 0; j < 16; j++) { v[j] = __expf(v[j] - m); s += v[j]; }
        #pragma unroll
        for (int o = 32; o; o >>= 1) s += __shfl_xor(s, o);
        const float inv = 1.f / s;
        #pragma unroll
        for (int j = 0; j < 16; j++) v[j] *= inv;
        uint pw[8];
        #pragma unroll
        for (int j = 0; j < 8; j++) pw[j] = pk(v[2 * j], v[2 * j + 1]);
        uint4 w0, w1;
        w0.x = pw[0]; w0.y = pw[1]; w0.z = pw[2]; w0.w = pw[3];
        w1.x = pw[4]; w1.y = pw[5]; w1.z = pw[6]; w1.w = pw[7];
        reinterpret_cast<uint4*>(row)[0] = w0;
        reinterpret_cast<uint4*>(row)[1] = w1;
        #pragma unroll
        for (int jj = 0; jj < 4; jj++) {
            float4 f4;
            f4.x = v[4 * jj]; f4.y = v[4 * jj + 1];
            f4.z = v[4 * jj + 2]; f4.w = v[4 * jj + 3];
            *reinterpret_cast<float4*>(&tile[h][(jj * 64 + lane) * 4]) = f4;
        }
    }
    __syncthreads();
    float* outp = attn_out + ((ll)b * SEQ + n) * SEQ * HEADS;
    #pragma unroll
    for (int jj = 0; jj < 4; jj++) {
        const int mm = t + 256 * jj;
        const int gm = mm >> 2;
        const int fi = ((gm & 3) * 64 + (gm >> 2)) * 4 + (mm & 3);
        float o16[16];
        #pragma unroll
        for (int h = 0; h < 16; h++) o16[h] = tile[h][fi];
        float4* dst = reinterpret_cast<float4*>(outp + (ll)mm * HEADS);
        #pragma unroll
        for (int q = 0; q < 4; q++) {
            float4 o4;
            o4.x = o16[4 * q]; o4.y = o16[4 * q + 1];
            o4.z = o16[4 * q + 2]; o4.w = o16[4 * q + 3];
            dst[q] = o4;
        }
    }
}

// ---------------------------------------------------------------------------
// LayerNorm (vectorized), optional bf16 copy.
// ---------------------------------------------------------------------------
__global__ __launch_bounds__(256) void ln_kernel(
    const float* __restrict__ a, const float* __restrict__ b, float coef,
    const float* __restrict__ g, const float* __restrict__ beta,
    float* __restrict__ out, ushort* __restrict__ out_bf)
{
    const int row = blockIdx.x;
    const int t = threadIdx.x;
    float4 av = reinterpret_cast<const float4*>(a + (ll)row * DIM)[t];
    float4 bv = reinterpret_cast<const float4*>(b + (ll)row * DIM)[t];
    float4 v;
    v.x = av.x + coef * bv.x; v.y = av.y + coef * bv.y;
    v.z = av.z + coef * bv.z; v.w = av.w + coef * bv.w;
    float s1 = v.x + v.y + v.z + v.w;
    float s2 = v.x * v.x + v.y * v.y + v.z * v.z + v.w * v.w;
    __shared__ float red[8];
    #pragma unroll
    for (int o = 32; o; o >>= 1) { s1 += __shfl_xor(s1, o); s2 += __shfl_xor(s2, o); }
    int w = t >> 6;
    if ((t & 63) == 0) { red[w] = s1; red[4 + w] = s2; }
    __syncthreads();
    s1 = red[0] + red[1] + red[2] + red[3];
    s2 = red[4] + red[5] + red[6] + red[7];
    float mu = s1 * (1.f / DIM);
    float var = s2 * (1.f / DIM) - mu * mu;
    float rs = rsqrtf(var + LNEPS);
    float4 gv = reinterpret_cast<const float4*>(g)[t];
    float4 be = reinterpret_cast<const float4*>(beta)[t];
    float4 o;
    o.x = (v.x - mu) * rs * gv.x + be.x;
    o.y = (v.y - mu) * rs * gv.y + be.y;
    o.z = (v.z - mu) * rs * gv.z + be.z;
    o.w = (v.w - mu) * rs * gv.w + be.w;
    reinterpret_cast<float4*>(out + (ll)row * DIM)[t] = o;
    if (out_bf) {
        us4 hv;
        hv.x = f2b(o.x); hv.y = f2b(o.y); hv.z = f2b(o.z); hv.w = f2b(o.w);
        reinterpret_cast<us4*>(out_bf + (ll)row * DIM)[t] = hv;
    }
}

// ---------------------------------------------------------------------------
// row softmax over 1024 contiguous fp32 -> bf16 out.
// ---------------------------------------------------------------------------
__global__ __launch_bounds__(256) void row_softmax(
    const float* __restrict__ logits, ushort* __restrict__ comb)
{
    const int row = blockIdx.x;
    const int t = threadIdx.x;
    float4 v = reinterpret_cast<const float4*>(logits + (ll)row * 1024)[t];
    float m = fmaxf(fmaxf(v.x, v.y), fmaxf(v.z, v.w));
    __shared__ float red[8];
    #pragma unroll
    for (int o = 32; o; o >>= 1) m = fmaxf(m, __shfl_xor(m, o));
    int w = t >> 6;
    if ((t & 63) == 0) red[w] = m;
    __syncthreads();
    m = fmaxf(fmaxf(red[0], red[1]), fmaxf(red[2], red[3]));
    __syncthreads();
    float4 e;
    e.x = __expf(v.x - m); e.y = __expf(v.y - m);
    e.z = __expf(v.z - m); e.w = __expf(v.w - m);
    float s = e.x + e.y + e.z + e.w;
    #pragma unroll
    for (int o = 32; o; o >>= 1) s += __shfl_xor(s, o);
    if ((t & 63) == 0) red[4 + w] = s;
    __syncthreads();
    s = red[4] + red[5] + red[6] + red[7];
    float inv = 1.f / s;
    us4 hv;
    hv.x = f2b(e.x * inv); hv.y = f2b(e.y * inv);
    hv.z = f2b(e.z * inv); hv.w = f2b(e.w * inv);
    reinterpret_cast<us4*>(comb + (ll)row * 1024)[t] = hv;
}

// ---------------------------------------------------------------------------
extern "C" void kernel_launch(void* const* d_in, const int* in_sizes, int n_in,
                              void* d_out, int out_size, void* d_ws, size_t ws_size,
                              hipStream_t stream)
{
    const float* x   = (const float*)d_in[0];
    const float* Wq  = (const float*)d_in[1];
    const float* bq  = (const float*)d_in[2];
    const float* Wkv = (const float*)d_in[3];
    const float* bkv = (const float*)d_in[4];
    const float* Wp  = (const float*)d_in[5];
    const float* bp  = (const float*)d_in[6];
    const float* g1  = (const float*)d_in[7];
    const float* b1  = (const float*)d_in[8];
    const float* phi = (const float*)d_in[9];
    const float* We1 = (const float*)d_in[10];
    const float* be1 = (const float*)d_in[11];
    const float* We2 = (const float*)d_in[12];
    const float* be2 = (const float*)d_in[13];
    const float* g2  = (const float*)d_in[14];
    const float* b2  = (const float*)d_in[15];

    float* out_y    = (float*)d_out;
    float* out_attn = out_y + (ll)BATCH * SEQ * DIM;

    // Workspace layout (float offsets, M1 = 1M floats).  Peak ~46.5M fl = 186 MB.
    const ll M1 = 1024 * 1024;
    float*  ws     = (float*)d_ws;
    ushort* x_bf   = (ushort*)(ws);                 // [0, 2M)
    ushort* WqkvT  = (ushort*)(ws + 2 * M1);        // [2, 3.5M)   3072x1024 bf16
    ushort* WpT    = (ushort*)(ws + 7 * M1 / 2);    // [3.5, 4M)
    ushort* phiT   = (ushort*)(ws + 4 * M1);        // [4, 4.5M)
    ushort* qkv_bf = (ushort*)(ws + 9 * M1 / 2);    // [4.5, 10.5M) 4096x3072 bf16
    ushort* vT     = (ushort*)(ws + 21 * M1 / 2);   // [10.5, 12.5M)
    ushort* p_bf   = (ushort*)(ws + 25 * M1 / 2);   // [12.5, 44.5M)
    float*  po     = ws + 25 * M1 / 2;              //   (after AV)
    float*  logitT = ws + 25 * M1 / 2;              //   (after LN; 4M fp32)
    ushort* ao_bf  = (ushort*)(ws + 89 * M1 / 2);   // [44.5, 46.5M)
    ushort* ymoeT  = (ushort*)(ws + 89 * M1 / 2);   //   (phase 2 alias)
    float*  x1     = ws + 33 * M1 / 2;              // [16.5, 20.5M)
    ushort* x1_bf  = (ushort*)(ws + 41 * M1 / 2);   // [20.5, 22.5M)
    ushort* x1T    = (ushort*)(ws + 45 * M1 / 2);   // [22.5, 24.5M)
    float*  logit  = ws + 49 * M1 / 2;              // [24.5, 28.5M)
    ushort* dispT  = (ushort*)(ws + 57 * M1 / 2);   // [28.5, 30.5M)
    ushort* comb   = (ushort*)(ws + 61 * M1 / 2);   // [30.5, 32.5M)
    ushort* slots  = (ushort*)(ws + 65 * M1 / 2);   // [32.5, 34.5M)
    ushort* hmid   = (ushort*)(ws + 69 * M1 / 2);   // [34.5, 42.5M)
    ushort* ymoe   = (ushort*)(ws + 85 * M1 / 2);   // [42.5, 44.5M)
    ushort* We1T   = (ushort*)(ws + 9 * M1 / 2);    // [4.5, 8.5M)  phase 2
    ushort* We2T   = (ushort*)(ws + 17 * M1 / 2);   // [8.5, 12.5M) phase 2
    float*  bqkv   = ws + 93 * M1 / 2;              // [46.5M, +3072)
    float*  moe    = ws;                            // [0, 4M) phase 2

    dim3 blk(256);

    // 0: bf16 conversions / weight transposes for the attention phase
    cvt_bf16<<<dim3(2048), blk, 0, stream>>>(x, x_bf);
    transpose_cvt<float,ushort><<<dim3(16, 16, 1), blk, 0, stream>>>(
        Wq, DIM, 0, 0, WqkvT, DIM, 0, 0, 1);
    transpose_cvt<float,ushort><<<dim3(32, 16, 1), blk, 0, stream>>>(
        Wkv, 2 * DIM, 0, 0, WqkvT + (ll)DIM * DIM, DIM, 0, 0, 1);
    transpose_cvt<float,ushort><<<dim3(16, 16, 1), blk, 0, stream>>>(
        Wp, DIM, 0, 0, WpT, DIM, 0, 0, 1);
    transpose_cvt<float,ushort><<<dim3(16, 16, 1), blk, 0, stream>>>(
        phi, ES, 0, 0, phiT, DIM, 0, 0, 1);
    concat_bias<<<dim3(12), blk, 0, stream>>>(bq, bkv, bqkv);

    // 1: fused QKV projection (N=3072, bf16 out)
    gemm2d<128,128,2,0,ushort><<<dim3(24, 32, 1), blk, 0, stream>>>(
        x_bf, DIM, 0, 0, WqkvT, DIM, 0, 0, bqkv, 0, 0,
        qkv_bf, 3 * DIM, 0, 0, DIM, 1, 1.f);

    // 2: vT[b,h][d][m] <- v slice of qkv
    transpose_cvt<ushort,ushort><<<dim3(1, 16, BATCH * HEADS), blk, 0, stream>>>(
        qkv_bf + 2 * DIM, 3 * DIM, (ll)SEQ * 3 * DIM, HD,
        vT, SEQ, (ll)HEADS * HD * SEQ, (ll)HD * SEQ, HEADS);

    // 3: scores p[b,n,h,m] = 0.125 * q_bh @ k_bh^T  (K=64 -> NK=1, NBUF=1)
    gemm2d<128,128,1,0,ushort><<<dim3(8, 8, BATCH * HEADS), blk, 0, stream>>>(
        qkv_bf, 3 * DIM, (ll)SEQ * 3 * DIM, HD,
        qkv_bf + DIM, 3 * DIM, (ll)SEQ * 3 * DIM, HD,
        nullptr, 0, 0,
        p_bf, HEADS * SEQ, (ll)SEQ * HEADS * SEQ, (ll)SEQ,
        HD, HEADS, 0.125f);

    // 4: softmax over m (in-place bf16) + fp32 bnmh attn output
    attn_softmax<<<dim3(SEQ, BATCH), blk, 0, stream>>>(p_bf, out_attn);

    // 5: ao = p_bh @ vT_bh^T   (BN=64, 48 KiB LDS -> 3 blocks/CU)
    gemm2d<128,64,2,0,ushort><<<dim3(1, 8, BATCH * HEADS), blk, 0, stream>>>(
        p_bf, HEADS * SEQ, (ll)SEQ * HEADS * SEQ, (ll)SEQ,
        vT, SEQ, (ll)HEADS * HD * SEQ, (ll)HD * SEQ,
        nullptr, 0, 0,
        ao_bf, DIM, (ll)SEQ * DIM, HD,
        SEQ, HEADS, 1.f);

    // 6: output projection (fp32 out)
    gemm2d<128,128,2,0,float><<<dim3(8, 32, 1), blk, 0, stream>>>(
        ao_bf, DIM, 0, 0, WpT, DIM, 0, 0, bp, 0, 0,
        po, DIM, 0, 0, DIM, 1, 1.f);
    // 7: x1 = LN(po + x)
    ln_kernel<<<dim3(NTOK), blk, 0, stream>>>(po, x, 1.0f, g1, b1, x1, x1_bf);

    // 7b: MoE weight transposes + x1T
    transpose_cvt<float,ushort><<<dim3(64, 16, 2), blk, 0, stream>>>(
        We1, HID, 0, (ll)DIM * HID, We1T, DIM, 0, (ll)HID * DIM, 2);
    transpose_cvt<float,ushort><<<dim3(16, 64, 2), blk, 0, stream>>>(
        We2, DIM, 0, (ll)HID * DIM, We2T, HID, 0, (ll)DIM * HID, 2);
    transpose_cvt<ushort,ushort><<<dim3(16, 16, BATCH), blk, 0, stream>>>(
        x1_bf, DIM, (ll)SEQ * DIM, 0, x1T, SEQ, (ll)DIM * SEQ, 0, 1);

    // 8: moe logits = x1 @ phi (fp32 out)
    gemm2d<128,128,2,0,float><<<dim3(8, 32, 1), blk, 0, stream>>>(
        x1_bf, DIM, 0, 0, phiT, DIM, 0, 0, nullptr, 0, 0,
        logit, ES, 0, 0, DIM, 1, 1.f);

    // 9: dispatch softmax over n (coalesced via fp32 transpose)
    transpose_cvt<float,float><<<dim3(16, 16, BATCH), blk, 0, stream>>>(
        logit, ES, (ll)SEQ * ES, 0, logitT, SEQ, (ll)ES * SEQ, 0, 1);
    row_softmax<<<dim3(BATCH * ES), blk, 0, stream>>>(logitT, dispT);
    // 10: combine softmax over es
    row_softmax<<<dim3(NTOK), blk, 0, stream>>>(logit, comb);

    // 11: slots[b] = dispT[b] @ x1T[b]^T
    gemm2d<128,128,2,0,ushort><<<dim3(8, 8, BATCH), blk, 0, stream>>>(
        dispT, SEQ, (ll)ES * SEQ, 0,
        x1T, SEQ, (ll)DIM * SEQ, 0,
        nullptr, 0, 0,
        slots, DIM, (ll)ES * DIM, 0,
        SEQ, 1, 1.f);

    // 12: hmid = gelu(slots @ We1 + be1)
    gemm2d<128,128,2,1,ushort><<<dim3(32, 4, BATCH * NEXP), blk, 0, stream>>>(
        slots, DIM, (ll)ES * DIM, (ll)NSLOT * DIM,
        We1T, DIM, 0, (ll)HID * DIM,
        be1, 0, HID,
        hmid, HID, (ll)ES * HID, (ll)NSLOT * HID,
        DIM, NEXP, 1.f);

    // 13: ymoe = hmid @ We2 + be2
    gemm2d<128,128,2,0,ushort><<<dim3(8, 4, BATCH * NEXP), blk, 0, stream>>>(
        hmid, HID, (ll)ES * HID, (ll)NSLOT * HID,
        We2T, HID, 0, (ll)DIM * HID,
        be2, 0, DIM,
        ymoe, DIM, (ll)ES * DIM, (ll)NSLOT * DIM,
        HID, NEXP, 1.f);

    // 13b: ymoeT[b][d][es] <- ymoe
    transpose_cvt<ushort,ushort><<<dim3(16, 16, BATCH), blk, 0, stream>>>(
        ymoe, DIM, (ll)ES * DIM, 0, ymoeT, ES, (ll)DIM * ES, 0, 1);

    // 14: moe[b] = comb[b] @ ymoeT[b]^T
    gemm2d<128,128,2,0,float><<<dim3(8, 8, BATCH), blk, 0, stream>>>(
        comb, ES, (ll)SEQ * ES, 0,
        ymoeT, ES, (ll)DIM * ES, 0,
        nullptr, 0, 0,
        moe, DIM, (ll)SEQ * DIM, 0,
        ES, 1, 1.f);

    // 15: y = LN(moe + 2*x1)
    ln_kernel<<<dim3(NTOK), blk, 0, stream>>>(moe, x1, 2.0f, g2, b2, out_y, nullptr);
}